// Round 1
// baseline (4359.299 us; speedup 1.0000x reference)
//
#include <hip/hip_runtime.h>
#include <math.h>

// Problem constants
#define B_    32
#define T_    21
#define STEPS 20
#define V_    10000
#define E_    512
#define A_    512
#define L_    512
#define P_    196
#define ENC_  2048
#define XK_   2560   // E + ENC
#define ZN_   2048   // 4*L

// ---- workspace layout (float offsets) ----
#define WS_ORD    0          // int[32]
#define WS_SLEN   32         // int[32]
#define WS_HBUF   64         // 2 * 32*512
#define WS_CBUF   32832      // 2 * 32*512
#define WS_MEAN   65600      // 32*2048
#define WS_A2     131136     // 32*512
#define WS_ALPHA  147520     // 32*196
#define WS_AWE    153792     // 32*2048
#define WS_X      219328     // 32*2560
#define WS_E      301248     // 32*196
#define WS_A1     307520     // 6272*512
#define WS_PZ     3518784    // 48 * 32*2048
#define WS_PP     6664512    // 8  * 32*10000
#define WS_PB     9224512    // 8  * 32*2048
#define WS_PA2    9748800    // 8  * 32*512
#define WS_PH     WS_PZ      // h0/c0 partials alias PZ (used before steps)

// ---- output layout (float offsets) ----
#define OUT_PRED  0
#define OUT_ALPHA 6400000    // 32*20*10000
#define OUT_ORDER 6525440    // + 32*20*196

// ============ order / lengths (stable descending argsort) ============
__global__ void k_order(const int* __restrict__ seqs, int* __restrict__ ord,
                        int* __restrict__ slen, float* __restrict__ out_ord)
{
    __shared__ int len[B_];
    int i = threadIdx.x;
    if (i < B_) {
        int c = 0;
        for (int t = 0; t < T_; ++t) c += (seqs[i * T_ + t] != 0) ? 1 : 0;
        len[i] = c;
    }
    __syncthreads();
    if (i < B_) {
        int li = len[i], r = 0;
        for (int j = 0; j < B_; ++j) {
            int lj = len[j];
            if (lj > li || (lj == li && j < i)) ++r;
        }
        ord[r]  = i;
        slen[r] = li - 1;          // decode steps for this (sorted) row
        out_ord[r] = (float)i;     // output 2
    }
}

// ============ mean-pool encoder (sorted) ============
__global__ void k_mean(const float* __restrict__ enc, const int* __restrict__ ord,
                       float* __restrict__ mean)
{
    int tid = blockIdx.x * 256 + threadIdx.x;   // 65536
    int b = tid >> 11, e = tid & 2047;
    const float* row = enc + (size_t)ord[b] * (P_ * ENC_) + e;
    float s = 0.f;
    for (int p = 0; p < P_; ++p) s += row[(size_t)p * ENC_];
    mean[tid] = s * (1.0f / 196.0f);
}

// ============ skinny GEMM partial: part[chunk][32][N] = X[32][K] @ W[K][N] ============
__global__ void sg_partial(const float* __restrict__ X, const float* __restrict__ W,
                           float* __restrict__ part, int K, int N, int kchunk, int chunk_ofs)
{
    const int n = blockIdx.x * 256 + threadIdx.x;
    const int c = blockIdx.y;
    const int k0 = c * kchunk;
    int k1 = k0 + kchunk; if (k1 > K) k1 = K;
    float acc[B_];
#pragma unroll
    for (int b = 0; b < B_; ++b) acc[b] = 0.f;
    if (n < N) {
        for (int k = k0; k < k1; k += 4) {
            float w0 = W[(size_t)(k + 0) * N + n];
            float w1 = W[(size_t)(k + 1) * N + n];
            float w2 = W[(size_t)(k + 2) * N + n];
            float w3 = W[(size_t)(k + 3) * N + n];
#pragma unroll
            for (int b = 0; b < B_; ++b) {
                const float4 xv = *reinterpret_cast<const float4*>(&X[(size_t)b * K + k]);
                acc[b] += xv.x * w0 + xv.y * w1 + xv.z * w2 + xv.w * w3;
            }
        }
        float* po = part + (size_t)(chunk_ofs + c) * (B_ * (size_t)N);
#pragma unroll
        for (int b = 0; b < B_; ++b) po[(size_t)b * N + n] = acc[b];
    }
}

// ============ h0/c0 combine ============
__global__ void k_h0c0(const float* __restrict__ ph, const float* __restrict__ bim,
                       const float* __restrict__ bic, float* __restrict__ h0,
                       float* __restrict__ c0)
{
    int tid = blockIdx.x * 256 + threadIdx.x;   // 32768
    int half = tid >> 14;
    int idx = tid & 16383;
    int l = idx & 511;
    int cofs = half ? 16 : 0;
    float s = 0.f;
    for (int c = 0; c < 16; ++c) s += ph[(size_t)(cofs + c) * (B_ * 512) + idx];
    if (half) c0[idx] = s + bic[l];
    else      h0[idx] = s + bim[l];
}

// ============ a1 = enc_sorted @ Wea + bea  (6272x512, K=2048) ============
__global__ void k_a1(const float* __restrict__ enc, const float* __restrict__ Wea,
                     const float* __restrict__ bea, const int* __restrict__ ord,
                     float* __restrict__ a1)
{
    __shared__ float As[16][64];   // [k][m]
    __shared__ float Bs[16][64];   // [k][n]
    const int tid = threadIdx.x;
    const int m0 = blockIdx.x * 64;
    const int n0 = blockIdx.y * 64;
    const int lm  = tid >> 2;            // A-load: m in tile
    const int lk  = (tid & 3) << 2;      // A-load: k in tile (x4)
    const int lkb = tid >> 4;            // B-load: k in tile
    const int lnb = (tid & 15) << 2;     // B-load: n in tile (x4)
    const int gm = m0 + lm;
    const int grow = ord[gm / P_] * P_ + (gm % P_);
    const float* Arow = enc + (size_t)grow * ENC_;
    const int tx = tid & 15, ty = tid >> 4;
    float acc[4][4];
#pragma unroll
    for (int i = 0; i < 4; ++i)
#pragma unroll
        for (int j = 0; j < 4; ++j) acc[i][j] = 0.f;

    for (int k0 = 0; k0 < ENC_; k0 += 16) {
        float4 av = *reinterpret_cast<const float4*>(Arow + k0 + lk);
        As[lk + 0][lm] = av.x; As[lk + 1][lm] = av.y;
        As[lk + 2][lm] = av.z; As[lk + 3][lm] = av.w;
        *reinterpret_cast<float4*>(&Bs[lkb][lnb]) =
            *reinterpret_cast<const float4*>(Wea + (size_t)(k0 + lkb) * 512 + n0 + lnb);
        __syncthreads();
#pragma unroll
        for (int k = 0; k < 16; ++k) {
            float4 a = *reinterpret_cast<const float4*>(&As[k][ty * 4]);
            float4 b = *reinterpret_cast<const float4*>(&Bs[k][tx * 4]);
            float am[4] = {a.x, a.y, a.z, a.w};
            float bn[4] = {b.x, b.y, b.z, b.w};
#pragma unroll
            for (int i = 0; i < 4; ++i)
#pragma unroll
                for (int j = 0; j < 4; ++j) acc[i][j] += am[i] * bn[j];
        }
        __syncthreads();
    }
    float4 be = *reinterpret_cast<const float4*>(bea + n0 + tx * 4);
    float bb4[4] = {be.x, be.y, be.z, be.w};
#pragma unroll
    for (int i = 0; i < 4; ++i) {
        float4 r;
        r.x = acc[i][0] + bb4[0]; r.y = acc[i][1] + bb4[1];
        r.z = acc[i][2] + bb4[2]; r.w = acc[i][3] + bb4[3];
        *reinterpret_cast<float4*>(a1 + (size_t)(m0 + ty * 4 + i) * 512 + n0 + tx * 4) = r;
    }
}

// ============ a2 combine: a2 = sum(part) + bga ============
__global__ void k_combine_a2(const float* __restrict__ pa2, const float* __restrict__ bga,
                             float* __restrict__ a2)
{
    int tid = blockIdx.x * 256 + threadIdx.x;   // 16384
    int l = tid & 511;
    float s = 0.f;
    for (int c = 0; c < 8; ++c) s += pa2[c * (B_ * 512) + tid];
    a2[tid] = s + bga[l];
}

// ============ e[b][p] = relu(a1[b][p][:] + a2[b][:]) . Wfa + bfa ============
__global__ void k_e(const float* __restrict__ a1, const float* __restrict__ a2,
                    const float* __restrict__ Wfa, const float* __restrict__ bfa,
                    float* __restrict__ evec)
{
    int wid = threadIdx.x >> 6, lane = threadIdx.x & 63;
    int o = blockIdx.x * 4 + wid;               // 0..6271
    int b = o / P_;
    const float4* arow = reinterpret_cast<const float4*>(a1 + (size_t)o * A_);
    const float4* a2r  = reinterpret_cast<const float4*>(a2 + (size_t)b * A_);
    const float4* wf   = reinterpret_cast<const float4*>(Wfa);
    float s = 0.f;
#pragma unroll
    for (int j = 0; j < 2; ++j) {
        int idx = lane + j * 64;
        float4 x = arow[idx], y = a2r[idx], w = wf[idx];
        float v0 = x.x + y.x; v0 = v0 > 0.f ? v0 : 0.f;
        float v1 = x.y + y.y; v1 = v1 > 0.f ? v1 : 0.f;
        float v2 = x.z + y.z; v2 = v2 > 0.f ? v2 : 0.f;
        float v3 = x.w + y.w; v3 = v3 > 0.f ? v3 : 0.f;
        s += v0 * w.x + v1 * w.y + v2 * w.z + v3 * w.w;
    }
    for (int m = 32; m > 0; m >>= 1) s += __shfl_xor(s, m, 64);
    if (lane == 0) evec[o] = s + bfa[0];
}

// ============ softmax over P per row; write alpha (ws) and masked alpha (out) ============
__global__ void k_softmax(const float* __restrict__ evec, float* __restrict__ alpha,
                          float* __restrict__ out_alpha, const int* __restrict__ slen, int t)
{
    __shared__ float red[256];
    int b = blockIdx.x, tid = threadIdx.x;
    float v = (tid < P_) ? evec[b * P_ + tid] : -1e30f;
    red[tid] = v; __syncthreads();
    for (int s2 = 128; s2 > 0; s2 >>= 1) {
        if (tid < s2) red[tid] = fmaxf(red[tid], red[tid + s2]);
        __syncthreads();
    }
    float mx = red[0]; __syncthreads();
    float ex = (tid < P_) ? expf(v - mx) : 0.f;
    red[tid] = ex; __syncthreads();
    for (int s2 = 128; s2 > 0; s2 >>= 1) {
        if (tid < s2) red[tid] += red[tid + s2];
        __syncthreads();
    }
    float inv = 1.0f / red[0];
    if (tid < P_) {
        float al = ex * inv;
        alpha[b * P_ + tid] = al;                       // unmasked (feeds awe)
        float mf = (slen[b] > t) ? 1.f : 0.f;
        out_alpha[((size_t)b * STEPS + t) * P_ + tid] = al * mf;
    }
}

// ============ awe[b][e] = sum_p alpha[b][p] * enc_sorted[b][p][e] ============
__global__ void k_awe(const float* __restrict__ alpha, const float* __restrict__ enc,
                      const int* __restrict__ ord, float* __restrict__ awe)
{
    int tid = blockIdx.x * 256 + threadIdx.x;   // 65536
    int b = tid >> 11, e = tid & 2047;
    const float* erow = enc + (size_t)ord[b] * (P_ * ENC_) + e;
    const float* al = alpha + b * P_;
    float s = 0.f;
    for (int p = 0; p < P_; ++p) s += al[p] * erow[(size_t)p * ENC_];
    awe[tid] = s;
}

// ============ x = [emb[tok], awe * sigmoid(c@Wb + bb)] ============
__global__ void k_buildx(const float* __restrict__ pb, const float* __restrict__ bb,
                         const float* __restrict__ awe, const float* __restrict__ emb,
                         const int* __restrict__ seqs, const int* __restrict__ ord,
                         int t, float* __restrict__ x)
{
    int tid = blockIdx.x * 256 + threadIdx.x;   // 81920
    int b = tid / XK_, j = tid - b * XK_;
    if (j < E_) {
        int tok = seqs[ord[b] * T_ + t];
        x[tid] = emb[(size_t)tok * E_ + j];
    } else {
        int jj = j - E_;
        int idx = b * ENC_ + jj;
        float s = 0.f;
        for (int c = 0; c < 8; ++c) s += pb[(size_t)c * (B_ * ENC_) + idx];
        float beta = 1.0f / (1.0f + expf(-(s + bb[jj])));
        x[tid] = awe[idx] * beta;
    }
}

// ============ LSTM gates from z partials; write c_new, h_new (masked) ============
__global__ void k_gates(const float* __restrict__ pz, const float* __restrict__ bl,
                        const float* __restrict__ c_in, const int* __restrict__ slen, int t,
                        float* __restrict__ c_out, float* __restrict__ h_out)
{
    int tid = blockIdx.x * 256 + threadIdx.x;   // 16384
    int b = tid >> 9, l = tid & 511;
    float zi = 0.f, zf = 0.f, zg = 0.f, zo = 0.f;
    for (int c = 0; c < 48; ++c) {
        const float* row = pz + (size_t)c * (B_ * ZN_) + b * ZN_;
        zi += row[l]; zf += row[512 + l]; zg += row[1024 + l]; zo += row[1536 + l];
    }
    zi += bl[l]; zf += bl[512 + l]; zg += bl[1024 + l]; zo += bl[1536 + l];
    float si = 1.f / (1.f + expf(-zi));
    float sf = 1.f / (1.f + expf(-zf));
    float so = 1.f / (1.f + expf(-zo));
    float g  = tanhf(zg);
    float cn = sf * c_in[tid] + si * g;
    float hn = so * tanhf(cn);
    float mf = (slen[b] > t) ? 1.f : 0.f;
    c_out[tid] = cn * mf;
    h_out[tid] = hn * mf;
}

// ============ pred combine: out[b][t][v] = (sum(part) + bo) * mf ============
__global__ void k_pred(const float* __restrict__ pp, const float* __restrict__ bo,
                       const int* __restrict__ slen, int t, float* __restrict__ out)
{
    int tid = blockIdx.x * 256 + threadIdx.x;   // 320000
    if (tid >= B_ * V_) return;
    int b = tid / V_, v = tid - b * V_;
    float s = 0.f;
    for (int c = 0; c < 8; ++c) s += pp[(size_t)c * (B_ * V_) + tid];
    s += bo[v];
    float mf = (slen[b] > t) ? 1.f : 0.f;
    out[((size_t)b * STEPS + t) * V_ + v] = s * mf;
}

extern "C" void kernel_launch(void* const* d_in, const int* in_sizes, int n_in,
                              void* d_out, int out_size, void* d_ws, size_t ws_size,
                              hipStream_t stream)
{
    const float* enc  = (const float*)d_in[0];
    const int*   seqs = (const int*)  d_in[1];
    const float* emb  = (const float*)d_in[2];
    const float* Wea  = (const float*)d_in[3];
    const float* bea  = (const float*)d_in[4];
    const float* Wga  = (const float*)d_in[5];
    const float* bga  = (const float*)d_in[6];
    const float* Wfa  = (const float*)d_in[7];
    const float* bfa  = (const float*)d_in[8];
    const float* Wl   = (const float*)d_in[9];
    const float* Ul   = (const float*)d_in[10];
    const float* bl   = (const float*)d_in[11];
    const float* Wim  = (const float*)d_in[12];
    const float* bim  = (const float*)d_in[13];
    const float* Wic  = (const float*)d_in[14];
    const float* bic  = (const float*)d_in[15];
    const float* Wb   = (const float*)d_in[16];
    const float* bb   = (const float*)d_in[17];
    const float* Wo   = (const float*)d_in[18];
    const float* bo   = (const float*)d_in[19];

    float* out = (float*)d_out;
    float* ws  = (float*)d_ws;
    int* ord  = (int*)(ws + WS_ORD);
    int* slen = (int*)(ws + WS_SLEN);

    // ---- prologue ----
    k_order<<<1, 64, 0, stream>>>(seqs, ord, slen, out + OUT_ORDER);
    k_mean<<<256, 256, 0, stream>>>(enc, ord, ws + WS_MEAN);
    sg_partial<<<dim3(2, 16), 256, 0, stream>>>(ws + WS_MEAN, Wim, ws + WS_PH, 2048, 512, 128, 0);
    sg_partial<<<dim3(2, 16), 256, 0, stream>>>(ws + WS_MEAN, Wic, ws + WS_PH, 2048, 512, 128, 16);
    k_h0c0<<<128, 256, 0, stream>>>(ws + WS_PH, bim, bic, ws + WS_HBUF, ws + WS_CBUF);
    k_a1<<<dim3(98, 8), 256, 0, stream>>>(enc, Wea, bea, ord, ws + WS_A1);

    // ---- decode steps ----
    for (int t = 0; t < STEPS; ++t) {
        float* h_in  = ws + WS_HBUF + (t & 1) * (B_ * L_);
        float* h_out = ws + WS_HBUF + ((t + 1) & 1) * (B_ * L_);
        float* c_in  = ws + WS_CBUF + (t & 1) * (B_ * L_);
        float* c_out = ws + WS_CBUF + ((t + 1) & 1) * (B_ * L_);

        sg_partial<<<dim3(2, 8), 256, 0, stream>>>(c_in, Wga, ws + WS_PA2, 512, 512, 64, 0);
        k_combine_a2<<<64, 256, 0, stream>>>(ws + WS_PA2, bga, ws + WS_A2);
        k_e<<<1568, 256, 0, stream>>>(ws + WS_A1, ws + WS_A2, Wfa, bfa, ws + WS_E);
        k_softmax<<<32, 256, 0, stream>>>(ws + WS_E, ws + WS_ALPHA, out + OUT_ALPHA, slen, t);
        k_awe<<<256, 256, 0, stream>>>(ws + WS_ALPHA, enc, ord, ws + WS_AWE);
        sg_partial<<<dim3(8, 8), 256, 0, stream>>>(c_in, Wb, ws + WS_PB, 512, 2048, 64, 0);
        k_buildx<<<320, 256, 0, stream>>>(ws + WS_PB, bb, ws + WS_AWE, emb, seqs, ord, t, ws + WS_X);
        sg_partial<<<dim3(8, 40), 256, 0, stream>>>(ws + WS_X, Wl, ws + WS_PZ, 2560, 2048, 64, 0);
        sg_partial<<<dim3(8, 8), 256, 0, stream>>>(h_in, Ul, ws + WS_PZ, 512, 2048, 64, 40);
        k_gates<<<64, 256, 0, stream>>>(ws + WS_PZ, bl, c_in, slen, t, c_out, h_out);
        sg_partial<<<dim3(40, 8), 256, 0, stream>>>(c_out, Wo, ws + WS_PP, 512, 10000, 64, 0);
        k_pred<<<1250, 256, 0, stream>>>(ws + WS_PP, bo, slen, t, out + OUT_PRED);
    }
}

// Round 3
// 2828.282 us; speedup vs baseline: 1.5413x; 1.5413x over previous
//
#include <hip/hip_runtime.h>
#include <math.h>

// Problem constants
#define B_    32
#define T_    21
#define STEPS 20
#define V_    10000
#define E_    512
#define A_    512
#define L_    512
#define P_    196
#define ENC_  2048
#define XK_   3072   // E + ENC + L (h appended for fused z GEMM)
#define ZN_   2048   // 4*L
#define ZCH   24     // K-chunks for z GEMM (3072/128)

// ---- workspace layout (float offsets) ----
#define WS_ORD    0          // int[32]
#define WS_SLEN   32         // int[32]
#define WS_HBUF   64         // 2 * 32*512
#define WS_CBUF   32832      // 2 * 32*512
#define WS_MEAN   65600      // 32*2048
#define WS_ALPHA  131136     // 32*196
#define WS_AWE    137408     // 32*2048
#define WS_X      202944     // 32*3072
#define WS_A1     301248     // 6272*512
#define WS_PZ     3512512    // 24 * 32*2048
#define WS_PP     5085376    // 4 * 32*10000
#define WS_PB     6365376    // 4 * 32*2048
#define WS_WEAT   6627520    // 512*2048 bf16 (as 524288 floats)
#define WS_PH     WS_PZ      // h0/c0 partials alias PZ (32 chunks * 32*512)

// ---- output layout (float offsets) ----
#define OUT_PRED  0
#define OUT_ALPHA 6400000    // 32*20*10000
#define OUT_ORDER 6525440    // + 32*20*196

typedef __attribute__((ext_vector_type(8))) short bf16x8;
typedef __attribute__((ext_vector_type(4))) float f32x4;

__device__ inline unsigned f2bf2(float lo, float hi) {
    unsigned a = __float_as_uint(lo), b = __float_as_uint(hi);
    a = (a + 0x7FFFu + ((a >> 16) & 1u)) >> 16;
    b = (b + 0x7FFFu + ((b >> 16) & 1u)) >> 16;
    return a | (b << 16);
}

// ============ order / lengths (stable descending argsort) ============
__global__ void k_order(const int* __restrict__ seqs, int* __restrict__ ord,
                        int* __restrict__ slen, float* __restrict__ out_ord)
{
    __shared__ int len[B_];
    int i = threadIdx.x;
    if (i < B_) {
        int c = 0;
        for (int t = 0; t < T_; ++t) c += (seqs[i * T_ + t] != 0) ? 1 : 0;
        len[i] = c;
    }
    __syncthreads();
    if (i < B_) {
        int li = len[i], r = 0;
        for (int j = 0; j < B_; ++j) {
            int lj = len[j];
            if (lj > li || (lj == li && j < i)) ++r;
        }
        ord[r]  = i;
        slen[r] = li - 1;
        out_ord[r] = (float)i;
    }
}

// ============ mean-pool encoder (sorted) ============
__global__ void k_mean(const float* __restrict__ enc, const int* __restrict__ ord,
                       float* __restrict__ mean)
{
    int tid = blockIdx.x * 256 + threadIdx.x;   // 65536
    int b = tid >> 11, e = tid & 2047;
    const float* row = enc + (size_t)ord[b] * (P_ * ENC_) + e;
    float s = 0.f;
    for (int p = 0; p < P_; ++p) s += row[(size_t)p * ENC_];
    mean[tid] = s * (1.0f / 196.0f);
}

// ============ cast + transpose Wea -> WeaT bf16 [512][2048] ============
__global__ void k_castWT(const float* __restrict__ Wea, unsigned short* __restrict__ WT)
{
    int tid = blockIdx.x * 256 + threadIdx.x;   // 1048576
    int n = tid >> 11, k = tid & 2047;
    float f = Wea[(size_t)k * 512 + n];
    unsigned u = __float_as_uint(f);
    WT[tid] = (unsigned short)((u + 0x7FFFu + ((u >> 16) & 1u)) >> 16);
}

// ============ a1 = enc_sorted @ Wea + bea via bf16 MFMA (6272x512, K=2048) ============
__global__ __launch_bounds__(256, 1) void k_a1_mfma(
    const float* __restrict__ enc, const unsigned short* __restrict__ WeaT,
    const float* __restrict__ bea, const int* __restrict__ ord,
    float* __restrict__ a1)
{
    __shared__ unsigned short As[128 * 40];   // [row][k0..31], stride 40 (pad never read)
    __shared__ unsigned short Bs[128 * 40];
    const int tid = threadIdx.x;
    const int lane = tid & 63, wave = tid >> 6;
    const int m0 = blockIdx.x * 128;
    const int n0 = blockIdx.y * 128;

    // staging: 512 chunks of 8 elems; thread handles chunks tid, tid+256
    const int c0 = tid, c1 = tid + 256;
    const int ar0 = c0 >> 2, ak0 = (c0 & 3) * 8;
    const int ar1 = c1 >> 2, ak1 = (c1 & 3) * 8;
    const int g0 = m0 + ar0, g1 = m0 + ar1;
    const float* Ag0 = enc + ((size_t)ord[g0 / P_] * P_ + (g0 % P_)) * ENC_ + ak0;
    const float* Ag1 = enc + ((size_t)ord[g1 / P_] * P_ + (g1 % P_)) * ENC_ + ak1;
    const unsigned short* Bg0 = WeaT + (size_t)(n0 + ar0) * ENC_ + ak0;
    const unsigned short* Bg1 = WeaT + (size_t)(n0 + ar1) * ENC_ + ak1;
    unsigned short* Aw0 = &As[ar0 * 40 + ak0];
    unsigned short* Aw1 = &As[ar1 * 40 + ak1];
    unsigned short* Bw0 = &Bs[ar0 * 40 + ak0];
    unsigned short* Bw1 = &Bs[ar1 * 40 + ak1];

    const int wm = (wave >> 1) * 64, wn = (wave & 1) * 64;
    f32x4 acc[4][4] = {};

    for (int k0 = 0; k0 < ENC_; k0 += 32) {
        float4 v0 = *reinterpret_cast<const float4*>(Ag0 + k0);
        float4 v1 = *reinterpret_cast<const float4*>(Ag0 + k0 + 4);
        float4 v2 = *reinterpret_cast<const float4*>(Ag1 + k0);
        float4 v3 = *reinterpret_cast<const float4*>(Ag1 + k0 + 4);
        uint4 pa0, pa1;
        pa0.x = f2bf2(v0.x, v0.y); pa0.y = f2bf2(v0.z, v0.w);
        pa0.z = f2bf2(v1.x, v1.y); pa0.w = f2bf2(v1.z, v1.w);
        pa1.x = f2bf2(v2.x, v2.y); pa1.y = f2bf2(v2.z, v2.w);
        pa1.z = f2bf2(v3.x, v3.y); pa1.w = f2bf2(v3.z, v3.w);
        uint4 pb0 = *reinterpret_cast<const uint4*>(Bg0 + k0);
        uint4 pb1 = *reinterpret_cast<const uint4*>(Bg1 + k0);
        __syncthreads();   // previous iter's ds_reads complete
        *reinterpret_cast<uint4*>(Aw0) = pa0;
        *reinterpret_cast<uint4*>(Aw1) = pa1;
        *reinterpret_cast<uint4*>(Bw0) = pb0;
        *reinterpret_cast<uint4*>(Bw1) = pb1;
        __syncthreads();
        // ONE mfma per (mt,nt) per 32-wide K block: lane holds k=(lane>>4)*8+j (0..31)
        {
            bf16x8 af[4], bfr[4];
            const int arow = wm + (lane & 15);
            const int brow = wn + (lane & 15);
            const int koff = (lane >> 4) * 8;
#pragma unroll
            for (int mt = 0; mt < 4; ++mt)
                af[mt] = *reinterpret_cast<const bf16x8*>(&As[(arow + mt * 16) * 40 + koff]);
#pragma unroll
            for (int nt = 0; nt < 4; ++nt)
                bfr[nt] = *reinterpret_cast<const bf16x8*>(&Bs[(brow + nt * 16) * 40 + koff]);
#pragma unroll
            for (int mt = 0; mt < 4; ++mt)
#pragma unroll
                for (int nt = 0; nt < 4; ++nt)
                    acc[mt][nt] = __builtin_amdgcn_mfma_f32_16x16x32_bf16(
                        af[mt], bfr[nt], acc[mt][nt], 0, 0, 0);
        }
    }
    const int rbase = (lane >> 4) * 4;
    const int cbase = lane & 15;
#pragma unroll
    for (int nt = 0; nt < 4; ++nt) {
        int col = n0 + wn + nt * 16 + cbase;
        float be = bea[col];
#pragma unroll
        for (int mt = 0; mt < 4; ++mt) {
            int row = m0 + wm + mt * 16 + rbase;
#pragma unroll
            for (int r = 0; r < 4; ++r)
                a1[(size_t)(row + r) * 512 + col] = acc[mt][nt][r] + be;
        }
    }
}

// ============ skinny GEMM partial, batch-split: 16 rows per thread ============
__global__ void sg_partial(const float* __restrict__ X, const float* __restrict__ W,
                           float* __restrict__ part, int K, int N, int kchunk, int chunk_ofs)
{
    const int n = blockIdx.x * 256 + threadIdx.x;
    const int c = blockIdx.y;
    const int bh = blockIdx.z;          // 0/1 -> batch half
    const int k0 = c * kchunk;
    int k1 = k0 + kchunk; if (k1 > K) k1 = K;
    float acc[16];
#pragma unroll
    for (int b = 0; b < 16; ++b) acc[b] = 0.f;
    if (n < N) {
        const float* Xb = X + (size_t)(bh * 16) * K;
        for (int k = k0; k < k1; k += 4) {
            float w0 = W[(size_t)(k + 0) * N + n];
            float w1 = W[(size_t)(k + 1) * N + n];
            float w2 = W[(size_t)(k + 2) * N + n];
            float w3 = W[(size_t)(k + 3) * N + n];
#pragma unroll
            for (int b = 0; b < 16; ++b) {
                const float4 xv = *reinterpret_cast<const float4*>(&Xb[(size_t)b * K + k]);
                acc[b] += xv.x * w0 + xv.y * w1 + xv.z * w2 + xv.w * w3;
            }
        }
        float* po = part + (size_t)(chunk_ofs + c) * (B_ * (size_t)N) + (size_t)(bh * 16) * N;
#pragma unroll
        for (int b = 0; b < 16; ++b) po[(size_t)b * N + n] = acc[b];
    }
}

// ============ fused z partial: z = x@Wl + h@Ul, K=3072 via concat ============
__global__ void sg_z(const float* __restrict__ X, const float* __restrict__ Wl,
                     const float* __restrict__ Ul, float* __restrict__ part)
{
    const int n = blockIdx.x * 256 + threadIdx.x;   // 2048
    const int c = blockIdx.y;                       // 24 chunks of 128
    const int bh = blockIdx.z;
    const float* W;
    int kw0;
    if (c < 20) { W = Wl; kw0 = c * 128; }
    else        { W = Ul; kw0 = (c - 20) * 128; }
    const int kx0 = c * 128;
    float acc[16];
#pragma unroll
    for (int b = 0; b < 16; ++b) acc[b] = 0.f;
    const float* Xb = X + (size_t)(bh * 16) * XK_ + kx0;
    for (int kk = 0; kk < 128; kk += 4) {
        float w0 = W[(size_t)(kw0 + kk + 0) * ZN_ + n];
        float w1 = W[(size_t)(kw0 + kk + 1) * ZN_ + n];
        float w2 = W[(size_t)(kw0 + kk + 2) * ZN_ + n];
        float w3 = W[(size_t)(kw0 + kk + 3) * ZN_ + n];
#pragma unroll
        for (int b = 0; b < 16; ++b) {
            const float4 xv = *reinterpret_cast<const float4*>(&Xb[(size_t)b * XK_ + kk]);
            acc[b] += xv.x * w0 + xv.y * w1 + xv.z * w2 + xv.w * w3;
        }
    }
    float* po = part + (size_t)c * (B_ * ZN_) + (size_t)(bh * 16) * ZN_;
#pragma unroll
    for (int b = 0; b < 16; ++b) po[(size_t)b * ZN_ + n] = acc[b];
}

// ============ h0/c0 combine ============
__global__ void k_h0c0(const float* __restrict__ ph, const float* __restrict__ bim,
                       const float* __restrict__ bic, float* __restrict__ h0,
                       float* __restrict__ c0)
{
    int tid = blockIdx.x * 256 + threadIdx.x;   // 32768
    int half = tid >> 14;
    int idx = tid & 16383;
    int l = idx & 511;
    int cofs = half ? 16 : 0;
    float s = 0.f;
    for (int c = 0; c < 16; ++c) s += ph[(size_t)(cofs + c) * (B_ * 512) + idx];
    if (half) c0[idx] = s + bic[l];
    else      h0[idx] = s + bim[l];
}

// ============ fused attention: a2 GEMM + e + softmax (one block per b) ============
__global__ __launch_bounds__(256, 1) void k_attn(
    const float* __restrict__ c_in, const float* __restrict__ Wga,
    const float* __restrict__ bga, const float* __restrict__ Wfa,
    const float* __restrict__ bfa, const float* __restrict__ a1,
    float* __restrict__ alpha, float* __restrict__ out_alpha,
    const int* __restrict__ slen, int t)
{
    __shared__ float cs[512];
    __shared__ float a2p[2][512];
    __shared__ float a2s[512];
    __shared__ float esh[224];
    __shared__ float red[256];
    const int b = blockIdx.x;
    const int tid = threadIdx.x;
    const int wave = tid >> 6, lane = tid & 63;

    cs[tid]       = c_in[b * 512 + tid];
    cs[tid + 256] = c_in[b * 512 + 256 + tid];
    __syncthreads();

    // ---- a2 = c @ Wga (split K in halves across thread groups) ----
    {
        const int half = tid >> 7, tl = tid & 127;
        const int n4 = tl * 4;
        float4 acc = {0.f, 0.f, 0.f, 0.f};
        const float* wbase = Wga + (size_t)(half * 256) * 512 + n4;
        for (int k = 0; k < 256; ++k) {
            float cv = cs[half * 256 + k];
            float4 w = *reinterpret_cast<const float4*>(wbase + (size_t)k * 512);
            acc.x += cv * w.x; acc.y += cv * w.y; acc.z += cv * w.z; acc.w += cv * w.w;
        }
        *reinterpret_cast<float4*>(&a2p[half][n4]) = acc;
    }
    __syncthreads();
    if (tid < 128) {
        const int n4 = tid * 4;
        float4 p0 = *reinterpret_cast<const float4*>(&a2p[0][n4]);
        float4 p1 = *reinterpret_cast<const float4*>(&a2p[1][n4]);
        float4 g  = *reinterpret_cast<const float4*>(bga + n4);
        float4 r;
        r.x = p0.x + p1.x + g.x; r.y = p0.y + p1.y + g.y;
        r.z = p0.z + p1.z + g.z; r.w = p0.w + p1.w + g.w;
        *reinterpret_cast<float4*>(&a2s[n4]) = r;
    }
    __syncthreads();

    // ---- e[p] = relu(a1[p]+a2) . Wfa : 16 lanes per p ----
    {
        const int grp = lane >> 4;        // 0..3
        const int sub = lane & 15;
        float4 a2r[8], wfr[8];
#pragma unroll
        for (int u = 0; u < 8; ++u) {
            int d = (u >> 1) * 128 + sub * 8 + (u & 1) * 4;
            a2r[u] = *reinterpret_cast<const float4*>(&a2s[d]);
            wfr[u] = *reinterpret_cast<const float4*>(Wfa + d);
        }
        const float bf0 = bfa[0];
        for (int pass = 0; pass < 13; ++pass) {
            const int p = pass * 16 + wave * 4 + grp;
            const int pc = p < P_ ? p : P_ - 1;
            const float* arow = a1 + ((size_t)b * P_ + pc) * 512;
            float s = 0.f;
#pragma unroll
            for (int u = 0; u < 8; ++u) {
                int d = (u >> 1) * 128 + sub * 8 + (u & 1) * 4;
                float4 x = *reinterpret_cast<const float4*>(arow + d);
                float4 av = a2r[u], wv = wfr[u];
                float v;
                v = x.x + av.x; v = v > 0.f ? v : 0.f; s += v * wv.x;
                v = x.y + av.y; v = v > 0.f ? v : 0.f; s += v * wv.y;
                v = x.z + av.z; v = v > 0.f ? v : 0.f; s += v * wv.z;
                v = x.w + av.w; v = v > 0.f ? v : 0.f; s += v * wv.w;
            }
            s += __shfl_xor(s, 1, 64);
            s += __shfl_xor(s, 2, 64);
            s += __shfl_xor(s, 4, 64);
            s += __shfl_xor(s, 8, 64);
            if (sub == 0 && p < P_) esh[p] = s + bf0;
        }
    }
    __syncthreads();

    // ---- softmax over esh[0..195] ----
    float v = (tid < P_) ? esh[tid] : -1e30f;
    red[tid] = v; __syncthreads();
    for (int s2 = 128; s2 > 0; s2 >>= 1) {
        if (tid < s2) red[tid] = fmaxf(red[tid], red[tid + s2]);
        __syncthreads();
    }
    float mx = red[0]; __syncthreads();
    float ex = (tid < P_) ? expf(v - mx) : 0.f;
    red[tid] = ex; __syncthreads();
    for (int s2 = 128; s2 > 0; s2 >>= 1) {
        if (tid < s2) red[tid] += red[tid + s2];
        __syncthreads();
    }
    float inv = 1.0f / red[0];
    if (tid < P_) {
        float al = ex * inv;
        alpha[b * P_ + tid] = al;
        float mf = (slen[b] > t) ? 1.f : 0.f;
        out_alpha[((size_t)b * STEPS + t) * P_ + tid] = al * mf;
    }
}

// ============ awe[b][e] = sum_p alpha[b][p] * enc_sorted[b][p][e] ============
__global__ void k_awe(const float* __restrict__ alpha, const float* __restrict__ enc,
                      const int* __restrict__ ord, float* __restrict__ awe)
{
    int tid = blockIdx.x * 256 + threadIdx.x;   // 65536
    int b = tid >> 11, e = tid & 2047;
    const float* erow = enc + (size_t)ord[b] * (P_ * ENC_) + e;
    const float* al = alpha + b * P_;
    float s = 0.f;
    for (int p = 0; p < P_; ++p) s += al[p] * erow[(size_t)p * ENC_];
    awe[tid] = s;
}

// ============ x = [emb[tok], awe * sigmoid(c@Wb + bb), h_in] ============
__global__ void k_buildx(const float* __restrict__ pb, const float* __restrict__ bb,
                         const float* __restrict__ awe, const float* __restrict__ emb,
                         const int* __restrict__ seqs, const int* __restrict__ ord,
                         const float* __restrict__ h_in, int t, float* __restrict__ x)
{
    int tid = blockIdx.x * 256 + threadIdx.x;   // 98304
    int b = tid / XK_, j = tid - b * XK_;
    if (j < E_) {
        int tok = seqs[ord[b] * T_ + t];
        x[tid] = emb[(size_t)tok * E_ + j];
    } else if (j < E_ + ENC_) {
        int jj = j - E_;
        int idx = b * ENC_ + jj;
        float s = 0.f;
        for (int c = 0; c < 4; ++c) s += pb[(size_t)c * (B_ * ENC_) + idx];
        float beta = 1.0f / (1.0f + expf(-(s + bb[jj])));
        x[tid] = awe[idx] * beta;
    } else {
        x[tid] = h_in[b * 512 + (j - E_ - ENC_)];
    }
}

// ============ LSTM gates from z partials; write c_new, h_new (masked) ============
__global__ void k_gates(const float* __restrict__ pz, const float* __restrict__ bl,
                        const float* __restrict__ c_in, const int* __restrict__ slen, int t,
                        float* __restrict__ c_out, float* __restrict__ h_out)
{
    int tid = blockIdx.x * 256 + threadIdx.x;   // 16384
    int b = tid >> 9, l = tid & 511;
    float zi = 0.f, zf = 0.f, zg = 0.f, zo = 0.f;
    for (int c = 0; c < ZCH; ++c) {
        const float* row = pz + (size_t)c * (B_ * ZN_) + b * ZN_;
        zi += row[l]; zf += row[512 + l]; zg += row[1024 + l]; zo += row[1536 + l];
    }
    zi += bl[l]; zf += bl[512 + l]; zg += bl[1024 + l]; zo += bl[1536 + l];
    float si = 1.f / (1.f + expf(-zi));
    float sf = 1.f / (1.f + expf(-zf));
    float so = 1.f / (1.f + expf(-zo));
    float g  = tanhf(zg);
    float cn = sf * c_in[tid] + si * g;
    float hn = so * tanhf(cn);
    float mf = (slen[b] > t) ? 1.f : 0.f;
    c_out[tid] = cn * mf;
    h_out[tid] = hn * mf;
}

// ============ pred combine ============
__global__ void k_pred(const float* __restrict__ pp, const float* __restrict__ bo,
                       const int* __restrict__ slen, int t, float* __restrict__ out)
{
    int tid = blockIdx.x * 256 + threadIdx.x;   // 320000
    if (tid >= B_ * V_) return;
    int b = tid / V_, v = tid - b * V_;
    float s = 0.f;
    for (int c = 0; c < 4; ++c) s += pp[(size_t)c * (B_ * V_) + tid];
    s += bo[v];
    float mf = (slen[b] > t) ? 1.f : 0.f;
    out[((size_t)b * STEPS + t) * V_ + v] = s * mf;
}

extern "C" void kernel_launch(void* const* d_in, const int* in_sizes, int n_in,
                              void* d_out, int out_size, void* d_ws, size_t ws_size,
                              hipStream_t stream)
{
    const float* enc  = (const float*)d_in[0];
    const int*   seqs = (const int*)  d_in[1];
    const float* emb  = (const float*)d_in[2];
    const float* Wea  = (const float*)d_in[3];
    const float* bea  = (const float*)d_in[4];
    const float* Wga  = (const float*)d_in[5];
    const float* bga  = (const float*)d_in[6];
    const float* Wfa  = (const float*)d_in[7];
    const float* bfa  = (const float*)d_in[8];
    const float* Wl   = (const float*)d_in[9];
    const float* Ul   = (const float*)d_in[10];
    const float* bl   = (const float*)d_in[11];
    const float* Wim  = (const float*)d_in[12];
    const float* bim  = (const float*)d_in[13];
    const float* Wic  = (const float*)d_in[14];
    const float* bic  = (const float*)d_in[15];
    const float* Wb   = (const float*)d_in[16];
    const float* bb   = (const float*)d_in[17];
    const float* Wo   = (const float*)d_in[18];
    const float* bo   = (const float*)d_in[19];

    float* out = (float*)d_out;
    float* ws  = (float*)d_ws;
    int* ord  = (int*)(ws + WS_ORD);
    int* slen = (int*)(ws + WS_SLEN);
    unsigned short* WeaT = (unsigned short*)(ws + WS_WEAT);

    // ---- prologue ----
    k_order<<<1, 64, 0, stream>>>(seqs, ord, slen, out + OUT_ORDER);
    k_mean<<<256, 256, 0, stream>>>(enc, ord, ws + WS_MEAN);
    sg_partial<<<dim3(2, 16, 2), 256, 0, stream>>>(ws + WS_MEAN, Wim, ws + WS_PH, 2048, 512, 128, 0);
    sg_partial<<<dim3(2, 16, 2), 256, 0, stream>>>(ws + WS_MEAN, Wic, ws + WS_PH, 2048, 512, 128, 16);
    k_h0c0<<<128, 256, 0, stream>>>(ws + WS_PH, bim, bic, ws + WS_HBUF, ws + WS_CBUF);
    k_castWT<<<4096, 256, 0, stream>>>(Wea, WeaT);
    k_a1_mfma<<<dim3(49, 4), 256, 0, stream>>>(enc, WeaT, bea, ord, ws + WS_A1);

    // ---- decode steps ----
    for (int t = 0; t < STEPS; ++t) {
        float* h_in  = ws + WS_HBUF + (t & 1) * (B_ * L_);
        float* h_out = ws + WS_HBUF + ((t + 1) & 1) * (B_ * L_);
        float* c_in  = ws + WS_CBUF + (t & 1) * (B_ * L_);
        float* c_out = ws + WS_CBUF + ((t + 1) & 1) * (B_ * L_);

        k_attn<<<32, 256, 0, stream>>>(c_in, Wga, bga, Wfa, bfa, ws + WS_A1,
                                       ws + WS_ALPHA, out + OUT_ALPHA, slen, t);
        k_awe<<<256, 256, 0, stream>>>(ws + WS_ALPHA, enc, ord, ws + WS_AWE);
        sg_partial<<<dim3(8, 4, 2), 256, 0, stream>>>(c_in, Wb, ws + WS_PB, 512, 2048, 128, 0);
        k_buildx<<<384, 256, 0, stream>>>(ws + WS_PB, bb, ws + WS_AWE, emb, seqs, ord,
                                          h_in, t, ws + WS_X);
        sg_z<<<dim3(8, ZCH, 2), 256, 0, stream>>>(ws + WS_X, Wl, Ul, ws + WS_PZ);
        k_gates<<<64, 256, 0, stream>>>(ws + WS_PZ, bl, c_in, slen, t, c_out, h_out);
        sg_partial<<<dim3(40, 4, 2), 256, 0, stream>>>(c_out, Wo, ws + WS_PP, 512, 10000, 128, 0);
        k_pred<<<1250, 256, 0, stream>>>(ws + WS_PP, bo, slen, t, out + OUT_PRED);
    }
}